// Round 6
// baseline (169.131 us; speedup 1.0000x reference)
//
#include <hip/hip_runtime.h>
#include <math.h>

#define NROWS   16384
#define IN_DIM  64
#define HID     256
#define OUT_DIM 64
#define NEXP    256
#define MT      128    // rows per tile (8 x 16); covers ~all experts in one pass
#define NT      8      // row tiles of 16
#define HP      264    // padded LDS row stride (bf16 elems): 528 B, 16B-aligned

typedef __attribute__((ext_vector_type(8))) short short8;   // 8 bf16 (4 VGPRs)
typedef __attribute__((ext_vector_type(4))) float f32x4;
typedef __attribute__((ext_vector_type(4))) unsigned uint4v;
typedef __attribute__((ext_vector_type(2))) unsigned uint2v;

// LDS-publish barrier: orders ds ops cross-wave WITHOUT draining vmcnt, so
// per-wave global weight loads stay in flight across layer boundaries
// (__syncthreads would emit s_waitcnt vmcnt(0) and kill the prefetch).
#define LBAR() do { \
    asm volatile("s_waitcnt lgkmcnt(0)" ::: "memory"); \
    __builtin_amdgcn_s_barrier(); } while (0)

// ---------------- parallel bucketing: memset + 3 small kernels ----------------

__global__ __launch_bounds__(256) void hist_k(const int* __restrict__ ind,
                                              int* __restrict__ hist) {
  int n = blockIdx.x * 256 + threadIdx.x;
  atomicAdd(&hist[ind[n]], 1);
}

__global__ __launch_bounds__(256) void scan_k(const int* __restrict__ hist,
                                              int* __restrict__ offsets,
                                              int* __restrict__ cur) {
  __shared__ int s[NEXP];
  int t = threadIdx.x;
  int h = hist[t];            // all reads complete before any write to cur/offsets
  s[t] = h;
  __syncthreads();
  for (int d = 1; d < NEXP; d <<= 1) {
    int v = (t >= d) ? s[t - d] : 0;
    __syncthreads();
    s[t] += v;
    __syncthreads();
  }
  int exc = s[t] - h;
  offsets[t] = exc;
  cur[t] = exc;
  if (t == NEXP - 1) offsets[NEXP] = s[t];
}

__global__ __launch_bounds__(256) void scatter_k(const int* __restrict__ ind,
                                                 int* __restrict__ cur,
                                                 int* __restrict__ rows) {
  int n = blockIdx.x * 256 + threadIdx.x;
  int p = atomicAdd(&cur[ind[n]], 1);
  rows[p] = n;
}

// ---------------- helpers ----------------

__device__ __forceinline__ unsigned bf16_rn(float f) {
  unsigned u = __builtin_bit_cast(unsigned, f);
  unsigned r = 0x7fffu + ((u >> 16) & 1u);
  return (u + r) >> 16;
}

__device__ __forceinline__ unsigned pk2(float a, float b) {
  return bf16_rn(a) | (bf16_rn(b) << 16);
}

__device__ __forceinline__ short8 cvt8(f32x4 w0, f32x4 w1) {
  uint4v u;
  u.x = pk2(w0.x, w0.y);
  u.y = pk2(w0.z, w0.w);
  u.z = pk2(w1.x, w1.y);
  u.w = pk2(w1.z, w1.w);
  return __builtin_bit_cast(short8, u);
}

__device__ __forceinline__ float fast_tanh(float v) {
  float e = __expf(2.f * v);
  return 1.f - 2.f * __builtin_amdgcn_rcpf(e + 1.f);
}

// ---------------- per-wave direct weight streaming (16 waves) ----------------
// Layers 1&2: wave w owns 16 neurons (rows w*16..+15). Weights stream straight
// global->VGPR, ring-3 software pipeline, all indices compile-time (full
// unroll), no barriers inside a layer.

template <int K>
__device__ __forceinline__ void layerN(const float* bp, f32x4 (&pre)[2][2],
                                       const unsigned short* Hin,
                                       int l15, int q, f32x4 (&acc)[NT]) {
  f32x4 wp[3][2];
  wp[0][0] = pre[0][0]; wp[0][1] = pre[0][1];
  wp[1][0] = pre[1][0]; wp[1][1] = pre[1][1];
  constexpr int KS = K / 32;
#pragma unroll
  for (int ks = 0; ks < KS; ks++) {
    const int cu = ks % 3;
    const int ld = (ks + 2) % 3;
    if (ks + 2 < KS) {
      wp[ld][0] = *(const f32x4*)(bp + (ks + 2) * 32);
      wp[ld][1] = *(const f32x4*)(bp + (ks + 2) * 32 + 4);
    }
    short8 a = cvt8(wp[cu][0], wp[cu][1]);
#pragma unroll
    for (int nt = 0; nt < NT; nt++) {
      short8 b = *(const short8*)&Hin[(nt * 16 + l15) * HP + ks * 32 + q * 8];
      acc[nt] = __builtin_amdgcn_mfma_f32_16x16x32_bf16(a, b, acc[nt], 0, 0, 0);
    }
  }
}

// layer3: 64 neurons, K=256 (8 K-steps). Wave w owns neuron group (w&3)*16..+15
// and row tiles {(w>>2)*2, (w>>2)*2+1}. Ring-2 pipeline, ks0 preloaded.
__device__ __forceinline__ void layer3_16(const float* bp, f32x4 (&pre)[2],
                                          const unsigned short* Hin,
                                          int w, int l15, int q,
                                          f32x4 (&accl)[2]) {
  f32x4 wp[2][2];
  wp[0][0] = pre[0]; wp[0][1] = pre[1];
  const int rt = w >> 2;
#pragma unroll
  for (int kk = 0; kk < 8; kk++) {
    const int cu = kk & 1;
    if (kk + 1 < 8) {
      wp[cu ^ 1][0] = *(const f32x4*)(bp + (kk + 1) * 32);
      wp[cu ^ 1][1] = *(const f32x4*)(bp + (kk + 1) * 32 + 4);
    }
    short8 a = cvt8(wp[cu][0], wp[cu][1]);
#pragma unroll
    for (int i = 0; i < 2; i++) {
      int nt = rt * 2 + i;
      short8 b = *(const short8*)&Hin[(nt * 16 + l15) * HP + kk * 32 + q * 8];
      accl[i] = __builtin_amdgcn_mfma_f32_16x16x32_bf16(a, b, accl[i], 0, 0, 0);
    }
  }
}

// tanh + pack + store h frags: frag nt -> H[row nt*16+l15][neurons w*16+q*4..+3]
__device__ __forceinline__ void write_h16(f32x4 (&acc)[NT], unsigned short* Hd,
                                          int w, int l15, int q) {
#pragma unroll
  for (int nt = 0; nt < NT; nt++) {
    uint2v v;
    v.x = pk2(fast_tanh(acc[nt].x), fast_tanh(acc[nt].y));
    v.y = pk2(fast_tanh(acc[nt].z), fast_tanh(acc[nt].w));
    *(uint2v*)&Hd[(nt * 16 + l15) * HP + w * 16 + q * 4] = v;
  }
}

// ---------------- main MLP kernel: 1 block/expert, 16 waves ------------------
// LDS = H only (67584 B). 16 waves/CU (4/SIMD) doubles latency coverage vs the
// 8-wave R2-R4 structures that all plateaued at ~42 us with every pipe idle.

__global__ __launch_bounds__(1024, 4) void mlp_k(
    const float* __restrict__ x,
    const float* __restrict__ W1, const float* __restrict__ b1,
    const float* __restrict__ W2, const float* __restrict__ b2,
    const float* __restrict__ Wl, const float* __restrict__ bl,
    const int* __restrict__ rows, const int* __restrict__ offsets,
    float* __restrict__ out) {
  __shared__ __align__(16) unsigned short H[MT * HP];  // 67584 B

  const int t = threadIdx.x;
  const int w = t >> 6;          // wave 0..15
  const int l15 = t & 15;
  const int q = (t >> 4) & 3;
  const int e = blockIdx.x;
  const int beg = offsets[e];
  const int cnt = offsets[e + 1] - beg;

  const float* W1e = W1 + (size_t)e * HID * IN_DIM;
  const float* W2e = W2 + (size_t)e * HID * HID;
  const float* Wle = Wl + (size_t)e * OUT_DIM * HID;

  // per-lane weight base pointers (row = neuron, col base = q*8)
  const float* bp1 = W1e + (size_t)(w * 16 + l15) * IN_DIM + q * 8;
  const float* bp2 = W2e + (size_t)(w * 16 + l15) * HID + q * 8;
  const float* bp3 = Wle + (size_t)((w & 3) * 16 + l15) * HID + q * 8;

  const f32x4 b1v = *(const f32x4*)(b1 + (size_t)e * HID + w * 16 + q * 4);
  const f32x4 b2v = *(const f32x4*)(b2 + (size_t)e * HID + w * 16 + q * 4);
  const f32x4 blv = *(const f32x4*)(bl + (size_t)e * OUT_DIM + (w & 3) * 16 + q * 4);

  const int sr = t >> 3;          // x-stage: row 0..127 (all 1024 threads active)
  const int sc = (t & 7) * 8;     // x-stage: col base (floats)

  for (int mt0 = 0; mt0 < cnt; mt0 += MT) {
    // ---- prologue: issue first-K-step weight loads for ALL layers so they
    // fly across the early barriers (LBAR never drains vmcnt).
    f32x4 p1[2][2], p2[2][2], p3[2];
#pragma unroll
    for (int k = 0; k < 2; k++) {
      p1[k][0] = *(const f32x4*)(bp1 + k * 32);
      p1[k][1] = *(const f32x4*)(bp1 + k * 32 + 4);
      p2[k][0] = *(const f32x4*)(bp2 + k * 32);
      p2[k][1] = *(const f32x4*)(bp2 + k * 32 + 4);
    }
    p3[0] = *(const f32x4*)(bp3);
    p3[1] = *(const f32x4*)(bp3 + 4);

    // ---- stage x tile (fp32 global -> bf16 LDS cols 0..63), zero-pad tail
    {
      int gm = mt0 + sr;
      bool val = gm < cnt;
      int r = val ? rows[beg + gm] : 0;
      const float* xr = x + (size_t)r * IN_DIM + sc;
      uint4v u;
      if (val) {
        f32x4 a0 = *(const f32x4*)(xr);
        f32x4 a1 = *(const f32x4*)(xr + 4);
        u.x = pk2(a0.x, a0.y); u.y = pk2(a0.z, a0.w);
        u.z = pk2(a1.x, a1.y); u.w = pk2(a1.z, a1.w);
      } else {
        u = (uint4v){0, 0, 0, 0};
      }
      *(uint4v*)&H[sr * HP + sc] = u;
    }
    LBAR();                                 // x visible to all waves

    // ---- layer1: x(K=64) -> h1(256), tanh
    f32x4 acc[NT];
#pragma unroll
    for (int nt = 0; nt < NT; nt++) acc[nt] = b1v;
    layerN<IN_DIM>(bp1, p1, H, l15, q, acc);
    LBAR();                                 // all x reads done
    write_h16(acc, H, w, l15, q);           // h1 (in place over x)
    LBAR();                                 // h1 visible

    // ---- layer2: h1(K=256) -> h2(256), tanh
#pragma unroll
    for (int nt = 0; nt < NT; nt++) acc[nt] = b2v;
    layerN<HID>(bp2, p2, H, l15, q, acc);
    LBAR();                                 // all h1 reads done
    write_h16(acc, H, w, l15, q);           // h2 (in place over h1)
    LBAR();                                 // h2 visible

    // ---- layer3: h2(K=256) -> out(64)
    f32x4 accl[2];
    accl[0] = blv; accl[1] = blv;
    layer3_16(bp3, p3, H, w, l15, q, accl);

#pragma unroll
    for (int i = 0; i < 2; i++) {
      int nt = (w >> 2) * 2 + i;
      int gm = mt0 + nt * 16 + l15;
      if (gm < cnt) {
        int r = rows[beg + gm];
        *(f32x4*)(out + (size_t)r * OUT_DIM + (w & 3) * 16 + q * 4) = accl[i];
      }
    }
    LBAR();  // protect H before next tile's x-stage (multi-tile case)
  }
}

// ---------------- launcher ----------------

extern "C" void kernel_launch(void* const* d_in, const int* in_sizes, int n_in,
                              void* d_out, int out_size, void* d_ws, size_t ws_size,
                              hipStream_t stream) {
  const float* x   = (const float*)d_in[0];
  const int*   ind = (const int*)d_in[1];
  const float* W1  = (const float*)d_in[2];
  const float* b1  = (const float*)d_in[3];
  const float* W2  = (const float*)d_in[4];
  const float* b2  = (const float*)d_in[5];
  const float* Wl  = (const float*)d_in[6];
  const float* bl  = (const float*)d_in[7];
  float* out = (float*)d_out;

  // ws layout (ints): offsets @0 (257) | hist/cur @260 (256) | rows @516 (16384)
  // hist and cur alias: scan_k reads all of hist before writing any of cur.
  int* offsets = (int*)d_ws;
  int* cur     = (int*)d_ws + 260;
  int* hist    = (int*)d_ws + 260;
  int* rows    = (int*)d_ws + 516;

  hipMemsetAsync(hist, 0, NEXP * sizeof(int), stream);
  hist_k<<<NROWS / 256, 256, 0, stream>>>(ind, hist);
  scan_k<<<1, 256, 0, stream>>>(hist, offsets, cur);
  scatter_k<<<NROWS / 256, 256, 0, stream>>>(ind, cur, rows);
  mlp_k<<<NEXP, 1024, 0, stream>>>(x, W1, b1, W2, b2, Wl, bl, rows, offsets, out);
}

// Round 7
// 169.005 us; speedup vs baseline: 1.0007x; 1.0007x over previous
//
#include <hip/hip_runtime.h>
#include <math.h>

#define NROWS   16384
#define IN_DIM  64
#define HID     256
#define OUT_DIM 64
#define NEXP    256
#define MT      112    // rows per tile (7 x 16); covers ~all experts in one pass
#define NT      7      // row tiles of 16
#define HP      264    // padded LDS row stride (bf16 elems): 528 B, 16B-aligned

typedef __attribute__((ext_vector_type(8))) short short8;   // 8 bf16 (4 VGPRs)
typedef __attribute__((ext_vector_type(4))) float f32x4;
typedef __attribute__((ext_vector_type(4))) unsigned uint4v;
typedef __attribute__((ext_vector_type(2))) unsigned uint2v;

// LDS-publish barrier: orders ds ops cross-wave WITHOUT draining vmcnt, so
// in-flight global weight loads survive layer boundaries (__syncthreads
// would emit s_waitcnt vmcnt(0) and kill the panel prefetch).
#define LBAR() do { \
    asm volatile("s_waitcnt lgkmcnt(0)" ::: "memory"); \
    __builtin_amdgcn_s_barrier(); } while (0)

// ---------------- parallel bucketing: memset + 3 small kernels ----------------

__global__ __launch_bounds__(256) void hist_k(const int* __restrict__ ind,
                                              int* __restrict__ hist) {
  int n = blockIdx.x * 256 + threadIdx.x;
  atomicAdd(&hist[ind[n]], 1);
}

__global__ __launch_bounds__(256) void scan_k(const int* __restrict__ hist,
                                              int* __restrict__ offsets,
                                              int* __restrict__ cur) {
  __shared__ int s[NEXP];
  int t = threadIdx.x;
  int h = hist[t];            // all reads complete before any write to cur/offsets
  s[t] = h;
  __syncthreads();
  for (int d = 1; d < NEXP; d <<= 1) {
    int v = (t >= d) ? s[t - d] : 0;
    __syncthreads();
    s[t] += v;
    __syncthreads();
  }
  int exc = s[t] - h;
  offsets[t] = exc;
  cur[t] = exc;
  if (t == NEXP - 1) offsets[NEXP] = s[t];
}

__global__ __launch_bounds__(256) void scatter_k(const int* __restrict__ ind,
                                                 int* __restrict__ cur,
                                                 int* __restrict__ rows) {
  int n = blockIdx.x * 256 + threadIdx.x;
  int p = atomicAdd(&cur[ind[n]], 1);
  rows[p] = n;
}

// ---------------- helpers ----------------

__device__ __forceinline__ unsigned bf16_rn(float f) {
  unsigned u = __builtin_bit_cast(unsigned, f);
  unsigned r = 0x7fffu + ((u >> 16) & 1u);
  return (u + r) >> 16;
}

__device__ __forceinline__ unsigned pk2(float a, float b) {
  return bf16_rn(a) | (bf16_rn(b) << 16);
}

__device__ __forceinline__ short8 cvt8(f32x4 w0, f32x4 w1) {
  uint4v u;
  u.x = pk2(w0.x, w0.y);
  u.y = pk2(w0.z, w0.w);
  u.z = pk2(w1.x, w1.y);
  u.w = pk2(w1.z, w1.w);
  return __builtin_bit_cast(short8, u);
}

__device__ __forceinline__ float fast_tanh(float v) {
  float e = __expf(2.f * v);
  return 1.f - 2.f * __builtin_amdgcn_rcpf(e + 1.f);
}

// ---------------- full-panel register prefetch machinery ----------------
// All panel arrays are indexed only by fully-unrolled loop counters (static
// after unroll -> registers, not scratch). Each load batch is >=4 independent
// dwordx4 loads -> one memory latency per batch, hidden under compute.

__device__ __forceinline__ void loadP1(const float* bp0, const float* bp1,
                                       f32x4 (&P)[2][2][2]) {
#pragma unroll
  for (int ks = 0; ks < 2; ks++) {
    P[ks][0][0] = *(const f32x4*)(bp0 + ks * 32);
    P[ks][0][1] = *(const f32x4*)(bp0 + ks * 32 + 4);
    P[ks][1][0] = *(const f32x4*)(bp1 + ks * 32);
    P[ks][1][1] = *(const f32x4*)(bp1 + ks * 32 + 4);
  }
}

template <int LO, int HI>
__device__ __forceinline__ void loadP2(const float* bp0, const float* bp1,
                                       f32x4 (&P)[8][2][2]) {
#pragma unroll
  for (int ks = LO; ks < HI; ks++) {
    P[ks][0][0] = *(const f32x4*)(bp0 + ks * 32);
    P[ks][0][1] = *(const f32x4*)(bp0 + ks * 32 + 4);
    P[ks][1][0] = *(const f32x4*)(bp1 + ks * 32);
    P[ks][1][1] = *(const f32x4*)(bp1 + ks * 32 + 4);
  }
}

template <int LO, int HI>
__device__ __forceinline__ void loadP3(const float* bp, f32x4 (&P)[8][2]) {
#pragma unroll
  for (int kk = LO; kk < HI; kk++) {
    P[kk][0] = *(const f32x4*)(bp + kk * 32);
    P[kk][1] = *(const f32x4*)(bp + kk * 32 + 4);
  }
}

// layer1 compute: K=64 (2 K-steps), panel fully resident.
__device__ __forceinline__ void l1_compute(const f32x4 (&P)[2][2][2],
                                           const unsigned short* Hin,
                                           int l15, int q, f32x4 (&acc)[2][NT]) {
#pragma unroll
  for (int ks = 0; ks < 2; ks++) {
    short8 a0 = cvt8(P[ks][0][0], P[ks][0][1]);
    short8 a1 = cvt8(P[ks][1][0], P[ks][1][1]);
#pragma unroll
    for (int nt = 0; nt < NT; nt++) {
      short8 b = *(const short8*)&Hin[(nt * 16 + l15) * HP + ks * 32 + q * 8];
      acc[0][nt] = __builtin_amdgcn_mfma_f32_16x16x32_bf16(a0, b, acc[0][nt], 0, 0, 0);
      acc[1][nt] = __builtin_amdgcn_mfma_f32_16x16x32_bf16(a1, b, acc[1][nt], 0, 0, 0);
    }
  }
}

// layer2 compute over K-step range [LO,HI): panel resident for that range.
template <int LO, int HI>
__device__ __forceinline__ void l2_compute(const f32x4 (&P)[8][2][2],
                                           const unsigned short* Hin,
                                           int l15, int q, f32x4 (&acc)[2][NT]) {
#pragma unroll
  for (int ks = LO; ks < HI; ks++) {
    short8 a0 = cvt8(P[ks][0][0], P[ks][0][1]);
    short8 a1 = cvt8(P[ks][1][0], P[ks][1][1]);
#pragma unroll
    for (int nt = 0; nt < NT; nt++) {
      short8 b = *(const short8*)&Hin[(nt * 16 + l15) * HP + ks * 32 + q * 8];
      acc[0][nt] = __builtin_amdgcn_mfma_f32_16x16x32_bf16(a0, b, acc[0][nt], 0, 0, 0);
      acc[1][nt] = __builtin_amdgcn_mfma_f32_16x16x32_bf16(a1, b, acc[1][nt], 0, 0, 0);
    }
  }
}

// layer3 compute: K=256 (8 K-steps), all weights already in registers.
// Wave w owns neurons (w&3)*16..+15; waves 0-3 cover row tiles 0..3,
// waves 4-7 cover tiles 4..6 (tile 7 does not exist at MT=112).
__device__ __forceinline__ void l3_compute(const f32x4 (&P)[8][2],
                                           const unsigned short* Hin,
                                           int w, int l15, int q,
                                           f32x4 (&accl)[4]) {
#pragma unroll
  for (int kk = 0; kk < 8; kk++) {
    short8 a = cvt8(P[kk][0], P[kk][1]);
#pragma unroll
    for (int i = 0; i < 4; i++) {
      int nt = (w >> 2) * 4 + i;
      if (nt < NT) {
        short8 b = *(const short8*)&Hin[(nt * 16 + l15) * HP + kk * 32 + q * 8];
        accl[i] = __builtin_amdgcn_mfma_f32_16x16x32_bf16(a, b, accl[i], 0, 0, 0);
      }
    }
  }
}

// tanh + pack + store h frags: frag (mt,nt) -> H[row nt*16+l15][neurons w*32+mt*16+q*4..+3]
__device__ __forceinline__ void write_h8(f32x4 (&acc)[2][NT], unsigned short* Hd,
                                         int w, int l15, int q) {
#pragma unroll
  for (int mt = 0; mt < 2; mt++)
#pragma unroll
    for (int nt = 0; nt < NT; nt++) {
      uint2v v;
      v.x = pk2(fast_tanh(acc[mt][nt].x), fast_tanh(acc[mt][nt].y));
      v.y = pk2(fast_tanh(acc[mt][nt].z), fast_tanh(acc[mt][nt].w));
      *(uint2v*)&Hd[(nt * 16 + l15) * HP + w * 32 + mt * 16 + q * 4] = v;
    }
}

// ---------------- main MLP kernel: 1 block/expert, panel-prefetched ----------
// 8 waves (2/SIMD, 256-VGPR budget). Each layer's per-wave weight panel is
// fully loaded into registers BEFORE the layer runs (batches of independent
// loads issued under the previous phase's compute) -> no dependent-load chain
// inside any layer; layer3 runs with zero global loads.

__global__ __launch_bounds__(512, 2) void mlp_k(
    const float* __restrict__ x,
    const float* __restrict__ W1, const float* __restrict__ b1,
    const float* __restrict__ W2, const float* __restrict__ b2,
    const float* __restrict__ Wl, const float* __restrict__ bl,
    const int* __restrict__ rows, const int* __restrict__ offsets,
    float* __restrict__ out) {
  __shared__ __align__(16) unsigned short H[MT * HP];  // 59136 B

  const int t = threadIdx.x;
  const int w = t >> 6;          // wave 0..7
  const int l15 = t & 15;
  const int q = (t >> 4) & 3;
  const int e = blockIdx.x;
  const int beg = offsets[e];
  const int cnt = offsets[e + 1] - beg;

  const float* W1e = W1 + (size_t)e * HID * IN_DIM;
  const float* W2e = W2 + (size_t)e * HID * HID;
  const float* Wle = Wl + (size_t)e * OUT_DIM * HID;

  // per-lane weight base pointers (row = neuron, col base = q*8)
  const float* bp1a = W1e + (size_t)(w * 32 + l15) * IN_DIM + q * 8;
  const float* bp1b = W1e + (size_t)(w * 32 + 16 + l15) * IN_DIM + q * 8;
  const float* bp2a = W2e + (size_t)(w * 32 + l15) * HID + q * 8;
  const float* bp2b = W2e + (size_t)(w * 32 + 16 + l15) * HID + q * 8;
  const float* bp3  = Wle + (size_t)((w & 3) * 16 + l15) * HID + q * 8;

  f32x4 b1v[2], b2v[2], blv;
#pragma unroll
  for (int mt = 0; mt < 2; mt++) {
    b1v[mt] = *(const f32x4*)(b1 + (size_t)e * HID + w * 32 + mt * 16 + q * 4);
    b2v[mt] = *(const f32x4*)(b2 + (size_t)e * HID + w * 32 + mt * 16 + q * 4);
  }
  blv = *(const f32x4*)(bl + (size_t)e * OUT_DIM + (w & 3) * 16 + q * 4);

  const int sr = t >> 2;          // x-stage: row 0..127 (only 0..111 active)
  const int sc = (t & 3) * 16;    // x-stage: col base

  for (int mt0 = 0; mt0 < cnt; mt0 += MT) {
    // ---- x-gather (rows -> x dependent chain) issued FIRST so its wait
    // count excludes as little as possible; then panel batches.
    f32x4 a0, a1, a2, a3;
    bool val = false;
    if (sr < MT) {
      int gm = mt0 + sr;
      val = gm < cnt;
      int r = val ? rows[beg + gm] : 0;
      const float* xr = x + (size_t)r * IN_DIM + sc;
      if (val) {
        a0 = *(const f32x4*)(xr);
        a1 = *(const f32x4*)(xr + 4);
        a2 = *(const f32x4*)(xr + 8);
        a3 = *(const f32x4*)(xr + 12);
      }
    }

    // ---- prologue panel batches (28 independent loads, one latency)
    f32x4 P1[2][2][2];   //  32 VGPR: layer1 full
    f32x4 P2[8][2][2];   // 128 VGPR when full: layer2
    f32x4 P3[8][2];      //  64 VGPR when full: layer3
    loadP1(bp1a, bp1b, P1);
    loadP2<0, 4>(bp2a, bp2b, P2);
    loadP3<0, 2>(bp3, P3);

    // ---- pack + stage x
    if (sr < MT) {
      uint4v u0, u1;
      if (val) {
        u0.x = pk2(a0.x, a0.y); u0.y = pk2(a0.z, a0.w);
        u0.z = pk2(a1.x, a1.y); u0.w = pk2(a1.z, a1.w);
        u1.x = pk2(a2.x, a2.y); u1.y = pk2(a2.z, a2.w);
        u1.z = pk2(a3.x, a3.y); u1.w = pk2(a3.z, a3.w);
      } else {
        u0 = (uint4v){0, 0, 0, 0};
        u1 = (uint4v){0, 0, 0, 0};
      }
      *(uint4v*)&H[sr * HP + sc] = u0;
      *(uint4v*)&H[sr * HP + sc + 8] = u1;
    }
    LBAR();                                 // x visible to all waves

    // ---- layer1: x(K=64) -> h1(256), tanh. P2 back half loads fly under it.
    loadP2<4, 8>(bp2a, bp2b, P2);
    f32x4 acc[2][NT];
#pragma unroll
    for (int mt = 0; mt < 2; mt++)
#pragma unroll
      for (int nt = 0; nt < NT; nt++) acc[mt][nt] = b1v[mt];
    l1_compute(P1, H, l15, q, acc);
    LBAR();                                 // all x reads done
    write_h8(acc, H, w, l15, q);            // h1 (in place over x)
    LBAR();                                 // h1 visible

    // ---- layer2: h1(K=256) -> h2(256), tanh. P3 back half loads fly under it.
#pragma unroll
    for (int mt = 0; mt < 2; mt++)
#pragma unroll
      for (int nt = 0; nt < NT; nt++) acc[mt][nt] = b2v[mt];
    l2_compute<0, 4>(P2, H, l15, q, acc);
    loadP3<2, 8>(bp3, P3);                  // issued after P2[0..3] dead
    l2_compute<4, 8>(P2, H, l15, q, acc);
    LBAR();                                 // all h1 reads done
    write_h8(acc, H, w, l15, q);            // h2 (in place over h1)
    LBAR();                                 // h2 visible

    // ---- layer3: h2(K=256) -> out(64); all weights in registers
    f32x4 accl[4];
#pragma unroll
    for (int i = 0; i < 4; i++) accl[i] = blv;
    l3_compute(P3, H, w, l15, q, accl);

#pragma unroll
    for (int i = 0; i < 4; i++) {
      int nt = (w >> 2) * 4 + i;
      if (nt < NT) {
        int gm = mt0 + nt * 16 + l15;
        if (gm < cnt) {
          int r = rows[beg + gm];
          *(f32x4*)(out + (size_t)r * OUT_DIM + (w & 3) * 16 + q * 4) = accl[i];
        }
      }
    }
    LBAR();  // protect H before next tile's x-stage (multi-tile case)
  }
}

// ---------------- launcher ----------------

extern "C" void kernel_launch(void* const* d_in, const int* in_sizes, int n_in,
                              void* d_out, int out_size, void* d_ws, size_t ws_size,
                              hipStream_t stream) {
  const float* x   = (const float*)d_in[0];
  const int*   ind = (const int*)d_in[1];
  const float* W1  = (const float*)d_in[2];
  const float* b1  = (const float*)d_in[3];
  const float* W2  = (const float*)d_in[4];
  const float* b2  = (const float*)d_in[5];
  const float* Wl  = (const float*)d_in[6];
  const float* bl  = (const float*)d_in[7];
  float* out = (float*)d_out;

  // ws layout (ints): offsets @0 (257) | hist/cur @260 (256) | rows @516 (16384)
  // hist and cur alias: scan_k reads all of hist before writing any of cur.
  int* offsets = (int*)d_ws;
  int* cur     = (int*)d_ws + 260;
  int* hist    = (int*)d_ws + 260;
  int* rows    = (int*)d_ws + 516;

  hipMemsetAsync(hist, 0, NEXP * sizeof(int), stream);
  hist_k<<<NROWS / 256, 256, 0, stream>>>(ind, hist);
  scan_k<<<1, 256, 0, stream>>>(hist, offsets, cur);
  scatter_k<<<NROWS / 256, 256, 0, stream>>>(ind, cur, rows);
  mlp_k<<<NEXP, 512, 0, stream>>>(x, W1, b1, W2, b2, Wl, bl, rows, offsets, out);
}